// Round 5
// baseline (39835.385 us; speedup 1.0000x reference)
//
#include <hip/hip_runtime.h>
#include <hip/hip_bf16.h>
#include <math.h>

// Problem constants
#define EMBD 400
#define HIDD 300
#define KEYD 128
#define VALD 128
#define NVOC 33
#define TT 256
#define BB 256
#define SS 512
#define WIH_LD 528          // EMB+VAL
#define GDIM 1200           // 4*HID
#define KTOT 428            // ctx(128)+h(300)

__device__ __forceinline__ float sigmoidf_(float x) {
    return 1.f / (1.f + expf(-x));
}

// ---------------- Precompute: E2[v][j] = b_ih[j] + b_hh[j] + emb[v]·W_ih[j][:400]
__global__ __launch_bounds__(256) void p_e2(
    const float* __restrict__ emb, const float* __restrict__ Wih,
    const float* __restrict__ bih, const float* __restrict__ bhh,
    float* __restrict__ E2)
{
    __shared__ float es[EMBD];
    const int v = blockIdx.x;
    for (int i = threadIdx.x; i < EMBD; i += 256) es[i] = emb[v * EMBD + i];
    __syncthreads();
    for (int j = threadIdx.x; j < GDIM; j += 256) {
        const float* wr = &Wih[(size_t)j * WIH_LD];
        float s0 = 0.f, s1 = 0.f, s2 = 0.f, s3 = 0.f;
        for (int e = 0; e < EMBD; e += 4) {
            s0 += es[e]     * wr[e];
            s1 += es[e + 1] * wr[e + 1];
            s2 += es[e + 2] * wr[e + 2];
            s3 += es[e + 3] * wr[e + 3];
        }
        E2[v * GDIM + j] = bih[j] + bhh[j] + ((s0 + s1) + (s2 + s3));
    }
}

// ---------------- Precompute: Wt[k][j] (fused, transposed) + phi_wT[i][k]
// Wt rows k<128: W_ih[:, 400+k] (ctx part); k>=128: W_hh[:, k-128] (h part).
__global__ __launch_bounds__(256) void p_wt(
    const float* __restrict__ Wih, const float* __restrict__ Whh,
    const float* __restrict__ phi_w,
    float* __restrict__ Wt, float* __restrict__ phi_wT)
{
    const int stride = gridDim.x * 256;
    for (int i = blockIdx.x * 256 + threadIdx.x; i < KTOT * GDIM; i += stride) {
        int k = i / GDIM, j = i - k * GDIM;
        Wt[i] = (k < KEYD) ? Wih[(size_t)j * WIH_LD + EMBD + k]
                           : Whh[(size_t)j * HIDD + (k - KEYD)];
    }
    for (int i = blockIdx.x * 256 + threadIdx.x; i < KEYD * HIDD; i += stride) {
        int k = i / HIDD, ii = i - k * HIDD;   // phi_w[k][ii]
        phi_wT[ii * KEYD + k] = phi_w[i];
    }
}

// ---------------- attend: C(q) D(energies) E(softmax) F(ctx) on LDS state ----
__device__ __forceinline__ void attend_steps(
    int b, int tid,
    const float* __restrict__ keys, const float* __restrict__ values,
    const float* __restrict__ phi_wT, const float* __restrict__ phi_b,
    float* h, float* ctx, float* q, float* att,
    float (*qp)[KEYD], float (*cpart)[VALD], float* red)
{
    // ---- C: q[k] = phi_b[k] + sum_i h[i]*phi_wT[i][k]  (8 i-slices x 128 k)
    {
        int k = tid & 127, slice = tid >> 7;            // 0..7
        int i0 = (slice * HIDD) >> 3;
        int i1 = ((slice + 1) * HIDD) >> 3;
        float s = 0.f;
        for (int i = i0; i < i1; ++i) s += h[i] * phi_wT[i * KEYD + k];
        qp[slice][k] = s;
    }
    __syncthreads();
    if (tid < KEYD) {
        float s = phi_b[tid];
        #pragma unroll
        for (int j = 0; j < 8; ++j) s += qp[j][tid];
        q[tid] = s;
    }
    __syncthreads();

    // ---- D: energies, 16 lanes per s, 64 s per pass, 8 passes
    {
        const int l16 = tid & 15, sg = tid >> 4;        // sg 0..63
        const float4* q4 = reinterpret_cast<const float4*>(q);
        const float4 qa = q4[l16 * 2], qb = q4[l16 * 2 + 1];
        #pragma unroll
        for (int p = 0; p < 8; ++p) {
            int s = p * 64 + sg;
            const float4* kp = reinterpret_cast<const float4*>(
                &keys[((size_t)s * BB + b) * KEYD]);
            float4 ka = kp[l16 * 2], kb = kp[l16 * 2 + 1];
            float e = ka.x * qa.x + ka.y * qa.y + ka.z * qa.z + ka.w * qa.w
                    + kb.x * qb.x + kb.y * qb.y + kb.z * qb.z + kb.w * qb.w;
            e += __shfl_xor(e, 1);
            e += __shfl_xor(e, 2);
            e += __shfl_xor(e, 4);
            e += __shfl_xor(e, 8);
            if (l16 == 0) att[s] = e;
        }
    }
    __syncthreads();

    // ---- E: softmax over att[0..511] (512 threads, 8 waves)
    {
        float ee = 0.f, pp = 0.f;
        if (tid < SS) {
            ee = att[tid];
            float m = ee;
            #pragma unroll
            for (int off = 32; off; off >>= 1) m = fmaxf(m, __shfl_xor(m, off));
            if ((tid & 63) == 0) red[tid >> 6] = m;
        }
        __syncthreads();
        float M = red[0];
        #pragma unroll
        for (int i = 1; i < 8; ++i) M = fmaxf(M, red[i]);
        if (tid < SS) {
            pp = expf(ee - M);
            float ss = pp;
            #pragma unroll
            for (int off = 32; off; off >>= 1) ss += __shfl_xor(ss, off);
            if ((tid & 63) == 0) red[8 + (tid >> 6)] = ss;
        }
        __syncthreads();
        float Sm = red[8];
        #pragma unroll
        for (int i = 1; i < 8; ++i) Sm += red[8 + i];
        if (tid < SS) att[tid] = pp * (1.f / Sm);
    }
    __syncthreads();

    // ---- F: ctx[v] = sum_s att[s]*V[s][b][v]; 32 s-groups x 32 v4-lanes
    {
        const int v4 = tid & 31, sg5 = tid >> 5;        // sg5 0..31
        float4 a = make_float4(0.f, 0.f, 0.f, 0.f);
        #pragma unroll 4
        for (int i = 0; i < 16; ++i) {
            int s = sg5 + i * 32;
            float w = att[s];
            const float4* vp = reinterpret_cast<const float4*>(
                &values[((size_t)s * BB + b) * VALD]);
            float4 v = vp[v4];
            a.x += w * v.x; a.y += w * v.y; a.z += w * v.z; a.w += w * v.w;
        }
        reinterpret_cast<float4*>(cpart[sg5])[v4] = a;
    }
    __syncthreads();
    if (tid < VALD) {
        float s = 0.f;
        #pragma unroll
        for (int g = 0; g < 32; ++g) s += cpart[g][tid];
        ctx[tid] = s;
    }
    __syncthreads();
}

// ---------------- main: one persistent block per batch row b ----------------
__global__ void __launch_bounds__(1024) decoder_main(
    const int* __restrict__ input, const float* __restrict__ keys,
    const float* __restrict__ values, const float* __restrict__ phi_b,
    const float* __restrict__ h0, const float* __restrict__ c0,
    const float* __restrict__ projw, const float* __restrict__ projb,
    const float* __restrict__ E2, const float* __restrict__ Wt,
    const float* __restrict__ phi_wT, float* __restrict__ out)
{
    const int b = blockIdx.x;
    const int tid = threadIdx.x;

    __shared__ float h[HIDD];
    __shared__ float c[HIDD];
    __shared__ float ctx[VALD];
    __shared__ float xin[KTOT];
    __shared__ float gl[GDIM];
    __shared__ __align__(16) float q[KEYD];
    __shared__ float att[SS];
    __shared__ float qp[8][KEYD];
    __shared__ __align__(16) float cpart[32][VALD];
    __shared__ float red[16];

    // init h, c from h0/c0 (broadcast rows)
    if (tid < HIDD) { h[tid] = h0[tid]; c[tid] = c0[tid]; }
    __syncthreads();

    // ctx(-1) = attend(h_init)
    attend_steps(b, tid, keys, values, phi_wT, phi_b, h, ctx, q, att, qp, cpart, red);

    #pragma unroll 1
    for (int t = 0; t < TT; ++t) {
        // ---- A: gates GEMV. xin = [ctx | h]; acc_j = E2[x][j] + xin·Wt[:,j]
        if (tid < KEYD) xin[tid] = ctx[tid];
        else if (tid < KTOT) xin[tid] = h[tid - KEYD];
        __syncthreads();

        const int xv = input[t * BB + b];
        const float* e2r = &E2[(size_t)xv * GDIM];
        float a0 = e2r[tid];
        float a1 = (tid < GDIM - 1024) ? e2r[1024 + tid] : 0.f;
        const float* W0 = Wt + tid;
        #pragma unroll 4
        for (int k = 0; k < KTOT; ++k) {
            float a = xin[k];
            a0 += a * W0[(size_t)k * GDIM];
            if (tid < GDIM - 1024) a1 += a * W0[(size_t)k * GDIM + 1024];
        }
        gl[tid] = a0;
        if (tid < GDIM - 1024) gl[1024 + tid] = a1;
        __syncthreads();

        // ---- B: LSTM cell update -> h(t), c(t) in LDS
        if (tid < HIDD) {
            float ig = sigmoidf_(gl[tid]);
            float fg = sigmoidf_(gl[300 + tid]);
            float gg = tanhf(gl[600 + tid]);
            float og = sigmoidf_(gl[900 + tid]);
            float cn = fg * c[tid] + ig * gg;
            c[tid] = cn;
            h[tid] = og * tanhf(cn);
        }
        __syncthreads();

        // ---- G: logits(t) = [h(t) | ctx(t-1)]·projw^T + projb  (before F!)
        if (tid < 528) {
            int v = tid >> 4, l = tid & 15;
            float s = 0.f;
            const float* pw = &projw[(size_t)v * KTOT];
            for (int k = l; k < KTOT; k += 16) {
                float a = (k < HIDD) ? h[k] : ctx[k - HIDD];
                s += a * pw[k];
            }
            s += __shfl_xor(s, 1);
            s += __shfl_xor(s, 2);
            s += __shfl_xor(s, 4);
            s += __shfl_xor(s, 8);
            if (l == 0 && v < NVOC)
                out[((size_t)t * BB + b) * NVOC + v] = s + projb[v];
        }
        // no sync needed before attend's first phase writes (qp), which is
        // disjoint from anything G reads; attend has its own syncs before
        // it overwrites ctx.

        // ---- C,D,E,F: ctx(t) = attend(h(t))  (skip on last step)
        if (t < TT - 1) {
            attend_steps(b, tid, keys, values, phi_wT, phi_b, h, ctx, q, att,
                         qp, cpart, red);
        }
    }
}

// =====================================================================
extern "C" void kernel_launch(void* const* d_in, const int* in_sizes, int n_in,
                              void* d_out, int out_size, void* d_ws, size_t ws_size,
                              hipStream_t stream)
{
    const int*   input     = (const int*)  d_in[0];
    const float* keys      = (const float*)d_in[1];
    const float* values    = (const float*)d_in[2];
    const float* embedding = (const float*)d_in[3];
    const float* phi_w     = (const float*)d_in[4];
    const float* phi_b     = (const float*)d_in[5];
    const float* h0        = (const float*)d_in[6];
    const float* c0        = (const float*)d_in[7];
    const float* W_ih      = (const float*)d_in[8];
    const float* b_ih      = (const float*)d_in[9];
    const float* W_hh      = (const float*)d_in[10];
    const float* b_hh      = (const float*)d_in[11];
    const float* proj_w    = (const float*)d_in[12];
    const float* proj_b    = (const float*)d_in[13];
    float* out = (float*)d_out;
    float* wsf = (float*)d_ws;

    float* E2     = wsf;                    // 33*1200   = 39600
    float* Wt     = E2 + NVOC * GDIM;       // 428*1200  = 513600
    float* phi_wT = Wt + KTOT * GDIM;       // 300*128   = 38400

    p_e2<<<NVOC, 256, 0, stream>>>(embedding, W_ih, b_ih, b_hh, E2);
    p_wt<<<2007, 256, 0, stream>>>(W_ih, W_hh, phi_w, Wt, phi_wT);
    decoder_main<<<BB, 1024, 0, stream>>>(input, keys, values, phi_b, h0, c0,
                                          proj_w, proj_b, E2, Wt, phi_wT, out);
}

// Round 6
// 20445.221 us; speedup vs baseline: 1.9484x; 1.9484x over previous
//
#include <hip/hip_runtime.h>
#include <hip/hip_bf16.h>
#include <math.h>

// Problem constants
#define EMBD 400
#define HIDD 300
#define KEYD 128
#define VALD 128
#define NVOC 33
#define TT 256
#define BB 256
#define SS 512
#define WIH_LD 528          // EMB+VAL
#define GDIM 1200           // 4*HID
#define KTOT 428            // ctx(128)+h(300)
#define NBLK 64             // 64 blocks x 4 batch rows each

__device__ __forceinline__ float sigmoidf_(float x) {
    return 1.f / (1.f + expf(-x));
}

// ---------------- Precompute: E2[v][j] = b_ih[j] + b_hh[j] + emb[v]·W_ih[j][:400]
__global__ __launch_bounds__(256) void p_e2(
    const float* __restrict__ emb, const float* __restrict__ Wih,
    const float* __restrict__ bih, const float* __restrict__ bhh,
    float* __restrict__ E2)
{
    __shared__ float es[EMBD];
    const int v = blockIdx.x;
    for (int i = threadIdx.x; i < EMBD; i += 256) es[i] = emb[v * EMBD + i];
    __syncthreads();
    for (int j = threadIdx.x; j < GDIM; j += 256) {
        const float* wr = &Wih[(size_t)j * WIH_LD];
        float s0 = 0.f, s1 = 0.f, s2 = 0.f, s3 = 0.f;
        for (int e = 0; e < EMBD; e += 4) {
            s0 += es[e]     * wr[e];
            s1 += es[e + 1] * wr[e + 1];
            s2 += es[e + 2] * wr[e + 2];
            s3 += es[e + 3] * wr[e + 3];
        }
        E2[v * GDIM + j] = bih[j] + bhh[j] + ((s0 + s1) + (s2 + s3));
    }
}

// ---------------- Precompute: WtX[k][j] (fused, transposed) + phi_wT[i][k]
// WtX rows k<128: W_ih[:, 400+k] (ctx part); k>=128: W_hh[:, k-128] (h part).
__global__ __launch_bounds__(256) void p_wt(
    const float* __restrict__ Wih, const float* __restrict__ Whh,
    const float* __restrict__ phi_w,
    float* __restrict__ WtX, float* __restrict__ phi_wT)
{
    const int stride = gridDim.x * 256;
    for (int i = blockIdx.x * 256 + threadIdx.x; i < KTOT * GDIM; i += stride) {
        int k = i / GDIM, j = i - k * GDIM;
        WtX[i] = (k < KEYD) ? Wih[(size_t)j * WIH_LD + EMBD + k]
                            : Whh[(size_t)j * HIDD + (k - KEYD)];
    }
    for (int i = blockIdx.x * 256 + threadIdx.x; i < KEYD * HIDD; i += stride) {
        int k = i / HIDD, ii = i - k * HIDD;   // phi_w[k][ii]
        phi_wT[ii * KEYD + k] = phi_w[i];
    }
}

// ---------------- attend for 4 rows: C(q joint) D(energies) E(softmax) F(ctx)
__device__ __forceinline__ void attend4(
    int tid, int tm, int tt, int bT,
    const float* __restrict__ keys, const float* __restrict__ values,
    const float* __restrict__ phi_wT, const float* __restrict__ phi_b,
    float (*h_s)[HIDD], float (*ctx_s)[VALD], float (*q_s)[KEYD],
    float* att, float* qp, float (*cpart)[8][VALD],
    float (*redA)[4], float (*redB)[4])
{
    // ---- C: q[b][k] = phi_b[k] + sum_i h[b][i]*phi_wT[i][k]
    // 512 threads: 4 i-slices x 128 k, 4 b-accumulators (phi_wT read ONCE/block)
    if (tid < 512) {
        const int slice = tid >> 7, k = tid & 127;
        const int i0 = slice * 75, i1 = i0 + 75;
        float a0 = 0.f, a1 = 0.f, a2 = 0.f, a3 = 0.f;
        #pragma unroll 5
        for (int i = i0; i < i1; ++i) {
            float w = phi_wT[i * KEYD + k];
            a0 += h_s[0][i] * w; a1 += h_s[1][i] * w;
            a2 += h_s[2][i] * w; a3 += h_s[3][i] * w;
        }
        qp[(0 * 4 + slice) * KEYD + k] = a0;
        qp[(1 * 4 + slice) * KEYD + k] = a1;
        qp[(2 * 4 + slice) * KEYD + k] = a2;
        qp[(3 * 4 + slice) * KEYD + k] = a3;
    }
    __syncthreads();
    if (tid < 512) {
        const int bi = tid >> 7, k = tid & 127;
        q_s[bi][k] = phi_b[k]
                   + qp[(bi * 4 + 0) * KEYD + k] + qp[(bi * 4 + 1) * KEYD + k]
                   + qp[(bi * 4 + 2) * KEYD + k] + qp[(bi * 4 + 3) * KEYD + k];
    }
    __syncthreads();

    // ---- D: energies per team; 16 lanes per s, 16 s-slots, 32 passes
    {
        const int l16 = tt & 15, sg = tt >> 4;
        const float4* q4 = reinterpret_cast<const float4*>(&q_s[tm][0]);
        const float4 qa = q4[l16 * 2], qb = q4[l16 * 2 + 1];
        #pragma unroll 4
        for (int p = 0; p < 32; ++p) {
            int s = p * 16 + sg;
            const float4* kp = reinterpret_cast<const float4*>(
                &keys[((size_t)s * BB + bT) * KEYD]);
            float4 ka = kp[l16 * 2], kb = kp[l16 * 2 + 1];
            float e = ka.x * qa.x + ka.y * qa.y + ka.z * qa.z + ka.w * qa.w
                    + kb.x * qb.x + kb.y * qb.y + kb.z * qb.z + kb.w * qb.w;
            e += __shfl_xor(e, 1);
            e += __shfl_xor(e, 2);
            e += __shfl_xor(e, 4);
            e += __shfl_xor(e, 8);
            if (l16 == 0) att[tm * SS + s] = e;
        }
    }
    __syncthreads();

    // ---- E: softmax per team (256 threads x 2 entries)
    {
        const int lane = tt & 63, wv = tt >> 6;   // 4 waves per team
        float e0 = att[tm * SS + tt], e1 = att[tm * SS + 256 + tt];
        float m = fmaxf(e0, e1);
        #pragma unroll
        for (int off = 32; off; off >>= 1) m = fmaxf(m, __shfl_xor(m, off));
        if (lane == 0) redA[tm][wv] = m;
        __syncthreads();
        float M = fmaxf(fmaxf(redA[tm][0], redA[tm][1]),
                        fmaxf(redA[tm][2], redA[tm][3]));
        float p0 = expf(e0 - M), p1 = expf(e1 - M);
        float ss = p0 + p1;
        #pragma unroll
        for (int off = 32; off; off >>= 1) ss += __shfl_xor(ss, off);
        if (lane == 0) redB[tm][wv] = ss;
        __syncthreads();
        float inv = 1.f / (redB[tm][0] + redB[tm][1] + redB[tm][2] + redB[tm][3]);
        att[tm * SS + tt] = p0 * inv;
        att[tm * SS + 256 + tt] = p1 * inv;
    }
    __syncthreads();

    // ---- F: ctx[b][v] = sum_s att[s]*V[s][b][v]; 8 s-groups x 32 v4-lanes
    {
        const int v4 = tt & 31, sg = tt >> 5;
        float4 a = make_float4(0.f, 0.f, 0.f, 0.f);
        #pragma unroll 8
        for (int i = 0; i < 64; ++i) {
            int s = sg * 64 + i;
            float w = att[tm * SS + s];
            const float4* vp = reinterpret_cast<const float4*>(
                &values[((size_t)s * BB + bT) * VALD]);
            float4 v = vp[v4];
            a.x += w * v.x; a.y += w * v.y; a.z += w * v.z; a.w += w * v.w;
        }
        reinterpret_cast<float4*>(&cpart[tm][sg][0])[v4] = a;
    }
    __syncthreads();
    if (tt < VALD) {
        float s = 0.f;
        #pragma unroll
        for (int g = 0; g < 8; ++g) s += cpart[tm][g][tt];
        ctx_s[tm][tt] = s;
    }
    __syncthreads();
}

// ---------------- main: one persistent block per 4 batch rows ----------------
__global__ void __launch_bounds__(1024, 4) decoder_main(
    const int* __restrict__ input, const float* __restrict__ keys,
    const float* __restrict__ values, const float* __restrict__ phi_b,
    const float* __restrict__ h0, const float* __restrict__ c0,
    const float* __restrict__ projw, const float* __restrict__ projb,
    const float* __restrict__ E2, const float* __restrict__ WtX,
    const float* __restrict__ phi_wT, float* __restrict__ out)
{
    const int tid = threadIdx.x;
    const int b0 = blockIdx.x * 4;
    const int tm = tid >> 8;           // team 0..3
    const int tt = tid & 255;
    const int bT = b0 + tm;            // this team's batch row

    __shared__ float h_s[4][HIDD];                     // 4800 B
    __shared__ float c_s[4][HIDD];                     // 4800 B
    __shared__ float ctx_s[4][VALD];                   // 2048 B
    __shared__ __align__(16) float xin4[KTOT][4];      // 6848 B
    __shared__ __align__(16) float uni[4 * GDIM];      // 19200 B: gl | att+qp
    __shared__ __align__(16) float q_s[4][KEYD];       // 2048 B
    __shared__ __align__(16) float cpart[4][8][VALD];  // 16384 B
    __shared__ float redA[4][4], redB[4][4];
    __shared__ int xv_s[4];
    // total ~56.3 KB (< 64 KB per-workgroup limit)

    float* att = uni;            // [4][512] (attend phases only)
    float* qp  = uni + 2048;     // [4][4][128] (attend C only)

    // ---- init h, c from broadcast rows
    for (int idx = tid; idx < 4 * HIDD; idx += 1024) {
        int bi = idx / HIDD, j = idx - bi * HIDD;
        h_s[bi][j] = h0[j];
        c_s[bi][j] = c0[j];
    }
    __syncthreads();

    // ctx(-1) = attend(h_init)
    attend4(tid, tm, tt, bT, keys, values, phi_wT, phi_b,
            h_s, ctx_s, q_s, att, qp, cpart, redA, redB);

    #pragma unroll 1
    for (int t = 0; t < TT; ++t) {
        // ---- stage xin = [ctx | h] interleaved by b (float4 per k), + x tokens
        if (tid < 4) xv_s[tid] = input[t * BB + b0 + tid];
        if (tid < KTOT) {
            const int k = tid;
            float4 x;
            x.x = (k < VALD) ? ctx_s[0][k] : h_s[0][k - VALD];
            x.y = (k < VALD) ? ctx_s[1][k] : h_s[1][k - VALD];
            x.z = (k < VALD) ? ctx_s[2][k] : h_s[2][k - VALD];
            x.w = (k < VALD) ? ctx_s[3][k] : h_s[3][k - VALD];
            *reinterpret_cast<float4*>(&xin4[k][0]) = x;
        }
        __syncthreads();

        // ---- gates GEMM: 600 threads own float2 j-columns; 4 b-rows each.
        // WtX read ONCE per block per step (the R5 killer was per-b re-reads).
        if (tid < 600) {
            const float2* Wt2 = reinterpret_cast<const float2*>(WtX);
            const int j2 = tid;
            float2 a0 = {0.f, 0.f}, a1 = {0.f, 0.f};
            float2 a2 = {0.f, 0.f}, a3 = {0.f, 0.f};
            #pragma unroll 8
            for (int k = 0; k < KTOT; ++k) {
                float4 x = *reinterpret_cast<const float4*>(&xin4[k][0]);
                float2 w = Wt2[(size_t)k * 600 + j2];
                a0.x += x.x * w.x; a0.y += x.x * w.y;
                a1.x += x.y * w.x; a1.y += x.y * w.y;
                a2.x += x.z * w.x; a2.y += x.z * w.y;
                a3.x += x.w * w.x; a3.y += x.w * w.y;
            }
            float2* gl2 = reinterpret_cast<float2*>(uni);
            gl2[0 * 600 + j2] = a0;
            gl2[1 * 600 + j2] = a1;
            gl2[2 * 600 + j2] = a2;
            gl2[3 * 600 + j2] = a3;
        }
        __syncthreads();

        // ---- cell update (E2 embedding-gather added here): 1200 items
        for (int idx = tid; idx < 4 * HIDD; idx += 1024) {
            int bi = idx / HIDD, j = idx - bi * HIDD;
            const float* glb = uni + bi * GDIM;
            const float* e2r = E2 + (size_t)xv_s[bi] * GDIM;
            float ig = sigmoidf_(glb[j]           + e2r[j]);
            float fg = sigmoidf_(glb[HIDD + j]    + e2r[HIDD + j]);
            float gg = tanhf    (glb[2*HIDD + j]  + e2r[2*HIDD + j]);
            float og = sigmoidf_(glb[3*HIDD + j]  + e2r[3*HIDD + j]);
            float cn = fg * c_s[bi][j] + ig * gg;
            c_s[bi][j] = cn;
            h_s[bi][j] = og * tanhf(cn);
        }
        __syncthreads();

        // ---- logits(t) on UPPER 512 threads (overlaps attend's q phase which
        // runs on the lower 512). Uses h(t) + ctx(t-1); attend only overwrites
        // ctx after multiple barriers, so this is race-free.
        if (tid >= 512) {
            const int l = tid & 3;
            const int r0 = (tid - 512) >> 2;          // 0..127
            #pragma unroll
            for (int rep = 0; rep < 2; ++rep) {
                if (rep == 1 && r0 >= 4) break;       // rows 128..131
                const int r = (rep == 0) ? r0 : 128 + r0;
                if (r >= 4 * NVOC) continue;
                const int bi = r / NVOC, v = r - bi * NVOC;
                const float* pw = projw + (size_t)v * KTOT;
                float s = 0.f;
                #pragma unroll 4
                for (int k = l; k < KTOT; k += 4) {
                    float a = (k < HIDD) ? h_s[bi][k] : ctx_s[bi][k - HIDD];
                    s += a * pw[k];
                }
                s += __shfl_xor(s, 1);
                s += __shfl_xor(s, 2);
                if (l == 0)
                    out[((size_t)t * BB + b0 + bi) * NVOC + v] = s + projb[v];
            }
        }

        // ---- ctx(t) = attend(h(t))  (skip on last step; uniform branch)
        if (t < TT - 1) {
            attend4(tid, tm, tt, bT, keys, values, phi_wT, phi_b,
                    h_s, ctx_s, q_s, att, qp, cpart, redA, redB);
        }
    }
}

// =====================================================================
extern "C" void kernel_launch(void* const* d_in, const int* in_sizes, int n_in,
                              void* d_out, int out_size, void* d_ws, size_t ws_size,
                              hipStream_t stream)
{
    const int*   input     = (const int*)  d_in[0];
    const float* keys      = (const float*)d_in[1];
    const float* values    = (const float*)d_in[2];
    const float* embedding = (const float*)d_in[3];
    const float* phi_w     = (const float*)d_in[4];
    const float* phi_b     = (const float*)d_in[5];
    const float* h0        = (const float*)d_in[6];
    const float* c0        = (const float*)d_in[7];
    const float* W_ih      = (const float*)d_in[8];
    const float* b_ih      = (const float*)d_in[9];
    const float* W_hh      = (const float*)d_in[10];
    const float* b_hh      = (const float*)d_in[11];
    const float* proj_w    = (const float*)d_in[12];
    const float* proj_b    = (const float*)d_in[13];
    float* out = (float*)d_out;
    float* wsf = (float*)d_ws;

    float* E2     = wsf;                    // 33*1200   = 39600 floats
    float* WtX    = E2 + NVOC * GDIM;       // 428*1200  = 513600
    float* phi_wT = WtX + KTOT * GDIM;      // 300*128   = 38400

    p_e2<<<NVOC, 256, 0, stream>>>(embedding, W_ih, b_ih, b_hh, E2);
    p_wt<<<2007, 256, 0, stream>>>(W_ih, W_hh, phi_w, WtX, phi_wT);
    decoder_main<<<NBLK, 1024, 0, stream>>>(input, keys, values, phi_b, h0, c0,
                                            proj_w, proj_b, E2, WtX, phi_wT, out);
}

// Round 7
// 17036.749 us; speedup vs baseline: 2.3382x; 1.2001x over previous
//
#include <hip/hip_runtime.h>
#include <hip/hip_bf16.h>
#include <math.h>

// Problem constants
#define EMBD 400
#define HIDD 300
#define KEYD 128
#define VALD 128
#define NVOC 33
#define TT 256
#define BB 256
#define SS 512
#define WIH_LD 528          // EMB+VAL
#define GDIM 1200           // 4*HID
#define KTOT 428            // ctx(128)+h(300)
#define KPAD 432            // padded to multiple of 8 for clean unroll
#define NBLK 64             // 64 blocks x 4 batch rows each

typedef unsigned int u32x4 __attribute__((ext_vector_type(4)));
typedef unsigned int u32x2 __attribute__((ext_vector_type(2)));

__device__ __forceinline__ float bflo(unsigned int u) {
    return __uint_as_float(u << 16);
}
__device__ __forceinline__ float bfhi(unsigned int u) {
    return __uint_as_float(u & 0xffff0000u);
}
__device__ __forceinline__ unsigned short f2bf(float x) {   // RNE, no NaN inputs
    unsigned int u = __float_as_uint(x);
    return (unsigned short)((u + 0x7fffu + ((u >> 16) & 1u)) >> 16);
}
__device__ __forceinline__ float sigmoidf_(float x) {
    return 1.f / (1.f + __expf(-x));
}
__device__ __forceinline__ float tanh_f(float x) {
    float ax = fabsf(x);
    if (ax > 15.f) return x > 0.f ? 1.f : -1.f;
    float e = __expf(2.f * x);
    return (e - 1.f) / (e + 1.f);
}

// ---------------- Precompute: E2[v][j] = b_ih[j]+b_hh[j]+emb[v]·W_ih[j][:400]
__global__ __launch_bounds__(256) void p_e2(
    const float* __restrict__ emb, const float* __restrict__ Wih,
    const float* __restrict__ bih, const float* __restrict__ bhh,
    float* __restrict__ E2)
{
    __shared__ float es[EMBD];
    const int v = blockIdx.x;
    for (int i = threadIdx.x; i < EMBD; i += 256) es[i] = emb[v * EMBD + i];
    __syncthreads();
    for (int j = threadIdx.x; j < GDIM; j += 256) {
        const float* wr = &Wih[(size_t)j * WIH_LD];
        float s0 = 0.f, s1 = 0.f, s2 = 0.f, s3 = 0.f;
        for (int e = 0; e < EMBD; e += 4) {
            s0 += es[e]     * wr[e];
            s1 += es[e + 1] * wr[e + 1];
            s2 += es[e + 2] * wr[e + 2];
            s3 += es[e + 3] * wr[e + 3];
        }
        E2[v * GDIM + j] = bih[j] + bhh[j] + ((s0 + s1) + (s2 + s3));
    }
}

// ---------------- Precompute: Wtb (bf16, fused+transposed, K padded) + phi_wT
__global__ __launch_bounds__(256) void p_wt(
    const float* __restrict__ Wih, const float* __restrict__ Whh,
    const float* __restrict__ phi_w,
    unsigned short* __restrict__ Wtb, float* __restrict__ phi_wT)
{
    const int stride = gridDim.x * 256;
    for (int i = blockIdx.x * 256 + threadIdx.x; i < KPAD * GDIM; i += stride) {
        int k = i / GDIM, j = i - k * GDIM;
        float v = 0.f;
        if (k < KEYD)      v = Wih[(size_t)j * WIH_LD + EMBD + k];
        else if (k < KTOT) v = Whh[(size_t)j * HIDD + (k - KEYD)];
        Wtb[i] = f2bf(v);
    }
    for (int i = blockIdx.x * 256 + threadIdx.x; i < KEYD * HIDD; i += stride) {
        int k = i / HIDD, ii = i - k * HIDD;   // phi_w[k][ii]
        phi_wT[ii * KEYD + k] = phi_w[i];
    }
}

// ---------------- Precompute: KV -> bf16, transposed to [b][s][dim]
__global__ __launch_bounds__(1024) void p_kv(
    const float* __restrict__ keys, const float* __restrict__ values,
    unsigned short* __restrict__ kbf, unsigned short* __restrict__ vbf)
{
    size_t i = (size_t)blockIdx.x * 1024 + threadIdx.x;  // S*B*K total exactly
    int s = (int)(i >> 15);
    int r = (int)(i & 32767);
    int b = r >> 7, k = r & 127;
    size_t d = (((size_t)b * SS + s) << 7) + k;
    kbf[d] = f2bf(keys[i]);
    vbf[d] = f2bf(values[i]);
}

// ---------------- attend for 4 rows ----------------
template<int KVBF>
__device__ __forceinline__ void attend4(
    int tid, int tm, int tt, int bT,
    const float* __restrict__ keysf, const float* __restrict__ valuesf,
    const unsigned short* __restrict__ kbf, const unsigned short* __restrict__ vbf,
    const float* __restrict__ phi_wT, const float* __restrict__ phi_b,
    float (*h_s)[HIDD], float (*ctx_s)[VALD], float (*q_s)[KEYD],
    float* att, float* qp, float (*cpart)[8][VALD],
    float (*redA)[4], float (*redB)[4], float (*xin4)[4])
{
    // ---- C: q[b][k] = phi_b[k] + sum_i h[b][i]*phi_wT[i][k] (lower 512 thr)
    if (tid < 512) {
        const int slice = tid >> 7, k = tid & 127;
        const int i0 = slice * 75, i1 = i0 + 75;
        float a0 = 0.f, a1 = 0.f, a2 = 0.f, a3 = 0.f;
        #pragma unroll 5
        for (int i = i0; i < i1; ++i) {
            float w = phi_wT[i * KEYD + k];
            a0 += h_s[0][i] * w; a1 += h_s[1][i] * w;
            a2 += h_s[2][i] * w; a3 += h_s[3][i] * w;
        }
        qp[(0 * 4 + slice) * KEYD + k] = a0;
        qp[(1 * 4 + slice) * KEYD + k] = a1;
        qp[(2 * 4 + slice) * KEYD + k] = a2;
        qp[(3 * 4 + slice) * KEYD + k] = a3;
    }
    __syncthreads();
    if (tid < 512) {
        const int bi = tid >> 7, k = tid & 127;
        q_s[bi][k] = phi_b[k]
                   + qp[(bi * 4 + 0) * KEYD + k] + qp[(bi * 4 + 1) * KEYD + k]
                   + qp[(bi * 4 + 2) * KEYD + k] + qp[(bi * 4 + 3) * KEYD + k];
    }
    __syncthreads();

    // ---- D: energies per team; 16 lanes per s
    {
        const int l16 = tt & 15, sg = tt >> 4;
        const float4* q4 = reinterpret_cast<const float4*>(&q_s[tm][0]);
        const float4 qa = q4[l16 * 2], qb = q4[l16 * 2 + 1];
        if (KVBF) {
            const unsigned short* krow = kbf + ((size_t)bT * SS) * KEYD;
            #pragma unroll 4
            for (int p = 0; p < 32; ++p) {
                int s = p * 16 + sg;
                const u32x4* kp = reinterpret_cast<const u32x4*>(
                    krow + (size_t)s * KEYD);
                u32x4 w = __builtin_nontemporal_load(kp + l16);
                float e = bflo(w.x) * qa.x + bfhi(w.x) * qa.y
                        + bflo(w.y) * qa.z + bfhi(w.y) * qa.w
                        + bflo(w.z) * qb.x + bfhi(w.z) * qb.y
                        + bflo(w.w) * qb.z + bfhi(w.w) * qb.w;
                e += __shfl_xor(e, 1);
                e += __shfl_xor(e, 2);
                e += __shfl_xor(e, 4);
                e += __shfl_xor(e, 8);
                if (l16 == 0) att[tm * SS + s] = e;
            }
        } else {
            #pragma unroll 4
            for (int p = 0; p < 32; ++p) {
                int s = p * 16 + sg;
                const float4* kp = reinterpret_cast<const float4*>(
                    &keysf[((size_t)s * BB + bT) * KEYD]);
                float4 ka = kp[l16 * 2], kb = kp[l16 * 2 + 1];
                float e = ka.x * qa.x + ka.y * qa.y + ka.z * qa.z + ka.w * qa.w
                        + kb.x * qb.x + kb.y * qb.y + kb.z * qb.z + kb.w * qb.w;
                e += __shfl_xor(e, 1);
                e += __shfl_xor(e, 2);
                e += __shfl_xor(e, 4);
                e += __shfl_xor(e, 8);
                if (l16 == 0) att[tm * SS + s] = e;
            }
        }
    }
    __syncthreads();

    // ---- E: softmax per team (256 threads x 2 entries)
    {
        const int lane = tt & 63, wv = tt >> 6;
        float e0 = att[tm * SS + tt], e1 = att[tm * SS + 256 + tt];
        float m = fmaxf(e0, e1);
        #pragma unroll
        for (int off = 32; off; off >>= 1) m = fmaxf(m, __shfl_xor(m, off));
        if (lane == 0) redA[tm][wv] = m;
        __syncthreads();
        float M = fmaxf(fmaxf(redA[tm][0], redA[tm][1]),
                        fmaxf(redA[tm][2], redA[tm][3]));
        float p0 = __expf(e0 - M), p1 = __expf(e1 - M);
        float ss = p0 + p1;
        #pragma unroll
        for (int off = 32; off; off >>= 1) ss += __shfl_xor(ss, off);
        if (lane == 0) redB[tm][wv] = ss;
        __syncthreads();
        float inv = 1.f / (redB[tm][0] + redB[tm][1] + redB[tm][2] + redB[tm][3]);
        att[tm * SS + tt] = p0 * inv;
        att[tm * SS + 256 + tt] = p1 * inv;
    }
    __syncthreads();

    // ---- F: ctx[b][v] = sum_s att[s]*V[s][b][v]
    {
        const int v4 = tt & 31, sg8 = tt >> 5;
        float4 a = make_float4(0.f, 0.f, 0.f, 0.f);
        if (KVBF) {
            const unsigned short* vrow = vbf + ((size_t)bT * SS) * VALD;
            #pragma unroll 8
            for (int i = 0; i < 64; ++i) {
                int s = sg8 * 64 + i;
                const u32x2* vp = reinterpret_cast<const u32x2*>(
                    vrow + (size_t)s * VALD);
                u32x2 w = __builtin_nontemporal_load(vp + v4);
                float wt = att[tm * SS + s];
                a.x += wt * bflo(w.x); a.y += wt * bfhi(w.x);
                a.z += wt * bflo(w.y); a.w += wt * bfhi(w.y);
            }
        } else {
            #pragma unroll 8
            for (int i = 0; i < 64; ++i) {
                int s = sg8 * 64 + i;
                float wt = att[tm * SS + s];
                const float4* vp = reinterpret_cast<const float4*>(
                    &valuesf[((size_t)s * BB + bT) * VALD]);
                float4 v = vp[v4];
                a.x += wt * v.x; a.y += wt * v.y;
                a.z += wt * v.z; a.w += wt * v.w;
            }
        }
        *reinterpret_cast<float4*>(&cpart[tm][sg8][v4 * 4]) = a;
    }
    __syncthreads();
    if (tt < VALD) {
        float s = 0.f;
        #pragma unroll
        for (int g = 0; g < 8; ++g) s += cpart[tm][g][tt];
        ctx_s[tm][tt] = s;
        xin4[tt][tm] = s;      // staged for next step's gates GEMM
    }
    __syncthreads();
}

// ---------------- main body: one persistent block per 4 batch rows ----------
template<int KVBF>
__device__ __forceinline__ void decoder_body(
    const int* __restrict__ input,
    const float* __restrict__ keysf, const float* __restrict__ valuesf,
    const unsigned short* __restrict__ kbf, const unsigned short* __restrict__ vbf,
    const float* __restrict__ phi_b, const float* __restrict__ h0,
    const float* __restrict__ c0, const float* __restrict__ projw,
    const float* __restrict__ projb, const float* __restrict__ E2,
    const unsigned short* __restrict__ Wtb, const float* __restrict__ phi_wT,
    float* __restrict__ out)
{
    const int tid = threadIdx.x;
    const int b0 = blockIdx.x * 4;
    const int tm = tid >> 8;           // team 0..3
    const int tt = tid & 255;
    const int bT = b0 + tm;

    __shared__ float h_s[4][HIDD];                     // 4800 B
    __shared__ float c_s[4][HIDD];                     // 4800 B
    __shared__ float ctx_s[4][VALD];                   // 2048 B
    __shared__ __align__(16) float xin4[KPAD][4];      // 6912 B
    __shared__ __align__(16) float uni[4 * GDIM];      // 19200 B: gl | att+qp
    __shared__ __align__(16) float q_s[4][KEYD];       // 2048 B
    __shared__ __align__(16) float cpart[4][8][VALD];  // 16384 B
    __shared__ float redA[4][4], redB[4][4];
    __shared__ int xv_s[4];

    float* att = uni;            // [4][512] (attend only)
    float* qp  = uni + 2048;     // [4][4][128] (attend C only)

    // ---- init h, c, xin4-h, xin4 pad
    for (int idx = tid; idx < 4 * HIDD; idx += 1024) {
        int bi = idx / HIDD, j = idx - bi * HIDD;
        float hv = h0[j];
        h_s[bi][j] = hv;
        c_s[bi][j] = c0[j];
        xin4[VALD + j][bi] = hv;
    }
    if (tid < 16) xin4[KTOT + (tid >> 2)][tid & 3] = 0.f;
    __syncthreads();

    // ctx(-1) = attend(h_init)
    attend4<KVBF>(tid, tm, tt, bT, keysf, valuesf, kbf, vbf, phi_wT, phi_b,
                  h_s, ctx_s, q_s, att, qp, cpart, redA, redB, xin4);

    #pragma unroll 1
    for (int t = 0; t < TT; ++t) {
        // ---- gates GEMM: 600 threads own bf16 j-pairs; 4 b-rows each
        if (tid < 600) {
            const unsigned int* Wp =
                reinterpret_cast<const unsigned int*>(Wtb) + tid;
            float2 a0 = {0.f, 0.f}, a1 = {0.f, 0.f};
            float2 a2 = {0.f, 0.f}, a3 = {0.f, 0.f};
            #pragma unroll 8
            for (int k = 0; k < KPAD; ++k) {
                float4 x = *reinterpret_cast<const float4*>(&xin4[k][0]);
                unsigned int w = Wp[(size_t)k * 600];
                float wlo = bflo(w), whi = bfhi(w);
                a0.x += x.x * wlo; a0.y += x.x * whi;
                a1.x += x.y * wlo; a1.y += x.y * whi;
                a2.x += x.z * wlo; a2.y += x.z * whi;
                a3.x += x.w * wlo; a3.y += x.w * whi;
            }
            float2* gl2 = reinterpret_cast<float2*>(uni);
            gl2[0 * 600 + tid] = a0;
            gl2[1 * 600 + tid] = a1;
            gl2[2 * 600 + tid] = a2;
            gl2[3 * 600 + tid] = a3;
        } else if (tid >= 1020) {
            xv_s[tid - 1020] = input[t * BB + b0 + (tid - 1020)];
        }
        __syncthreads();

        // ---- cell update (+E2 embedding gather); writes h_s, c_s, xin4-h
        for (int idx = tid; idx < 4 * HIDD; idx += 1024) {
            int bi = idx / HIDD, j = idx - bi * HIDD;
            const float* glb = uni + bi * GDIM;
            const float* e2r = E2 + (size_t)xv_s[bi] * GDIM;
            float ig = sigmoidf_(glb[j]            + e2r[j]);
            float fg = sigmoidf_(glb[HIDD + j]     + e2r[HIDD + j]);
            float gg = tanh_f   (glb[2 * HIDD + j] + e2r[2 * HIDD + j]);
            float og = sigmoidf_(glb[3 * HIDD + j] + e2r[3 * HIDD + j]);
            float cn = fg * c_s[bi][j] + ig * gg;
            c_s[bi][j] = cn;
            float hv = og * tanh_f(cn);
            h_s[bi][j] = hv;
            xin4[VALD + j][bi] = hv;
        }
        __syncthreads();

        // ---- logits(t) on upper 512 threads (overlaps attend C on lower 512)
        // projw read once per block: (v, 16-lane) slots, 4 b-accumulators.
        if (tid >= 512) {
            const int idx = tid - 512;
            const int l = idx & 15;
            const int vs = idx >> 4;              // 0..31
            #pragma unroll
            for (int rep = 0; rep < 2; ++rep) {
                const int v = vs + rep * 32;
                if (v < NVOC) {
                    const float* pw = projw + (size_t)v * KTOT;
                    float s0 = 0.f, s1 = 0.f, s2 = 0.f, s3 = 0.f;
                    for (int k = l; k < KTOT; k += 16) {
                        float w = pw[k];
                        float u0 = (k < HIDD) ? h_s[0][k] : ctx_s[0][k - HIDD];
                        float u1 = (k < HIDD) ? h_s[1][k] : ctx_s[1][k - HIDD];
                        float u2 = (k < HIDD) ? h_s[2][k] : ctx_s[2][k - HIDD];
                        float u3 = (k < HIDD) ? h_s[3][k] : ctx_s[3][k - HIDD];
                        s0 += w * u0; s1 += w * u1; s2 += w * u2; s3 += w * u3;
                    }
                    #pragma unroll
                    for (int off = 8; off; off >>= 1) {
                        s0 += __shfl_xor(s0, off);
                        s1 += __shfl_xor(s1, off);
                        s2 += __shfl_xor(s2, off);
                        s3 += __shfl_xor(s3, off);
                    }
                    if (l == 0) {
                        float pb = projb[v];
                        size_t ob = ((size_t)t * BB + b0) * NVOC + v;
                        out[ob]            = s0 + pb;
                        out[ob + NVOC]     = s1 + pb;
                        out[ob + 2 * NVOC] = s2 + pb;
                        out[ob + 3 * NVOC] = s3 + pb;
                    }
                }
            }
        }

        // ---- ctx(t) = attend(h(t))  (skip on last step; uniform branch)
        if (t < TT - 1) {
            attend4<KVBF>(tid, tm, tt, bT, keysf, valuesf, kbf, vbf, phi_wT,
                          phi_b, h_s, ctx_s, q_s, att, qp, cpart, redA, redB,
                          xin4);
        }
    }
}

__global__ void __launch_bounds__(1024, 4) decoder_bf(
    const int* input, const float* keysf, const float* valuesf,
    const unsigned short* kbf, const unsigned short* vbf,
    const float* phi_b, const float* h0, const float* c0,
    const float* projw, const float* projb, const float* E2,
    const unsigned short* Wtb, const float* phi_wT, float* out)
{
    decoder_body<1>(input, keysf, valuesf, kbf, vbf, phi_b, h0, c0,
                    projw, projb, E2, Wtb, phi_wT, out);
}

__global__ void __launch_bounds__(1024, 4) decoder_f32(
    const int* input, const float* keysf, const float* valuesf,
    const unsigned short* kbf, const unsigned short* vbf,
    const float* phi_b, const float* h0, const float* c0,
    const float* projw, const float* projb, const float* E2,
    const unsigned short* Wtb, const float* phi_wT, float* out)
{
    decoder_body<0>(input, keysf, valuesf, kbf, vbf, phi_b, h0, c0,
                    projw, projb, E2, Wtb, phi_wT, out);
}

// =====================================================================
extern "C" void kernel_launch(void* const* d_in, const int* in_sizes, int n_in,
                              void* d_out, int out_size, void* d_ws, size_t ws_size,
                              hipStream_t stream)
{
    const int*   input     = (const int*)  d_in[0];
    const float* keys      = (const float*)d_in[1];
    const float* values    = (const float*)d_in[2];
    const float* embedding = (const float*)d_in[3];
    const float* phi_w     = (const float*)d_in[4];
    const float* phi_b     = (const float*)d_in[5];
    const float* h0        = (const float*)d_in[6];
    const float* c0        = (const float*)d_in[7];
    const float* W_ih      = (const float*)d_in[8];
    const float* b_ih      = (const float*)d_in[9];
    const float* W_hh      = (const float*)d_in[10];
    const float* b_hh      = (const float*)d_in[11];
    const float* proj_w    = (const float*)d_in[12];
    const float* proj_b    = (const float*)d_in[13];
    float* out = (float*)d_out;

    char* base = (char*)d_ws;
    size_t off = 0;
    auto alloc = [&](size_t bytes) {
        size_t o = off;
        off = (off + bytes + 255) & ~(size_t)255;
        return o;
    };
    size_t oE2   = alloc((size_t)NVOC * GDIM * 4);       // 158 KB
    size_t oPhi  = alloc((size_t)HIDD * KEYD * 4);       // 154 KB
    size_t oWtb  = alloc((size_t)KPAD * GDIM * 2);       // 1.04 MB
    size_t small_total = off;
    size_t oKbf  = alloc((size_t)SS * BB * KEYD * 2);    // 33.6 MB
    size_t oVbf  = alloc((size_t)SS * BB * VALD * 2);    // 33.6 MB
    size_t full_total = off;

    float* E2 = (float*)(base + oE2);
    float* phi_wT = (float*)(base + oPhi);
    unsigned short* Wtb = (unsigned short*)(base + oWtb);
    unsigned short* kbf = (unsigned short*)(base + oKbf);
    unsigned short* vbf = (unsigned short*)(base + oVbf);

    const bool kvbf = (ws_size >= full_total);
    (void)small_total;

    p_e2<<<NVOC, 256, 0, stream>>>(embedding, W_ih, b_ih, b_hh, E2);
    p_wt<<<2048, 256, 0, stream>>>(W_ih, W_hh, phi_w, Wtb, phi_wT);

    if (kvbf) {
        p_kv<<<(SS * BB * KEYD) / 1024, 1024, 0, stream>>>(keys, values, kbf, vbf);
        decoder_bf<<<NBLK, 1024, 0, stream>>>(
            input, keys, values, kbf, vbf, phi_b, h0, c0,
            proj_w, proj_b, E2, Wtb, phi_wT, out);
    } else {
        decoder_f32<<<NBLK, 1024, 0, stream>>>(
            input, keys, values, (const unsigned short*)nullptr,
            (const unsigned short*)nullptr, phi_b, h0, c0,
            proj_w, proj_b, E2, Wtb, phi_wT, out);
    }
}